// Round 16
// baseline (294.208 us; speedup 1.0000x reference)
//
#include <hip/hip_runtime.h>
#include <hip/hip_bf16.h>

#define NUM_GRAPHS 64
#define NODES 256
#define EDGES 1024
#define NTOT (NUM_GRAPHS * NODES)
#define DF 512
#define HF 1024
#define HP 256
#define NC 10
#define INF32 0xFFFFFFFFu
#define DONE_MAGIC 0x5A17C0DEu

typedef short bf16x8 __attribute__((ext_vector_type(8)));
typedef float f32x4 __attribute__((ext_vector_type(4)));

__device__ __forceinline__ unsigned short bf16r(float f) {
    __hip_bfloat16 h = __float2bfloat16(f);
    return *(unsigned short*)&h;
}
__device__ __forceinline__ unsigned encf(float x) {
    union { float f; unsigned u; } c; c.f = x;
    return (c.u & 0x80000000u) ? ~c.u : (c.u | 0x80000000u);
}

// ============ fully fused kernel: 64 blocks (1/graph) x 512 threads =======
__global__ __launch_bounds__(512, 2) void k_all(
    const float* __restrict__ x, const int* __restrict__ edges,
    const float* __restrict__ w1, const float* __restrict__ b1,
    const float* __restrict__ w2, const float* __restrict__ b2,
    const float* __restrict__ wp0, const float* __restrict__ bp0,
    const float* __restrict__ wp1, const float* __restrict__ bp1,
    const float* __restrict__ wh, const float* __restrict__ bh,
    unsigned* __restrict__ doneflags, unsigned short* __restrict__ w1f,
    float* __restrict__ out)
{
    // --- LDS: phase-overlapped slab + persistent arrays -------------------
    __shared__ __align__(16) char smem[34816];   // gemm 32KB | cvt 16KB | pers 2x17408
    __shared__ float fS[NODES];                  // sigmoid(f) per vertex
    __shared__ float dl[2][NODES];               // deaths per sign
    __shared__ float pp[2][HP];                  // pooled phi per sign
    __shared__ int cntA[2], chgA[2];

    const int tid = threadIdx.x;
    const int g = blockIdx.x;
    const int lane = tid & 63;
    const int wv = tid >> 6;          // 0..7
    const int l15 = lane & 15, quad = lane >> 4;

    // ---- Phase 0: convert this block's slice of w1 -> w1f (frag order) ---
    {
        float* ls = (float*)smem + (tid >> 8) * 2048;   // 2 x 8KB slabs
        const int ltid = tid & 255;
#pragma unroll
        for (int it = 0; it < 2; ++it) {
            int obid = g * 4 + it * 2 + (tid >> 8);
            int cg = obid >> 2, kq = obid & 3;
            int c = ltid & 15, kr = ltid >> 4;
#pragma unroll
            for (int it2 = 0; it2 < 8; ++it2) {
                int kk = it2 * 16 + kr;
                ls[kk * 16 + c] = w1[(size_t)(kq * 128 + kk) * HF + cg * 16 + c];
            }
            __syncthreads();
            int tt = ltid >> 6, n16 = (ltid >> 2) & 15, q = ltid & 3;
            unsigned short v[8];
#pragma unroll
            for (int j = 0; j < 8; ++j)
                v[j] = bf16r(ls[(tt * 32 + q * 8 + j) * 16 + n16]);
            size_t off = ((size_t)(cg * 16 + kq * 4 + tt) * 16 + n16) * 32 + q * 8;
#pragma unroll
            for (int j = 0; j < 8; ++j) w1f[off + j] = v[j];
            __syncthreads();
        }
        __syncthreads();
        if (tid == 0) {
            __threadfence();
            __hip_atomic_store(&doneflags[g], DONE_MAGIC, __ATOMIC_RELEASE,
                               __HIP_MEMORY_SCOPE_AGENT);
        }
    }

    // ---- Phase 0.5: A fragments from x (overlaps other blocks' cvt) ------
    // wave wv owns rows g*256 + wv*32 .. +31 (two 16-row subtiles)
    bf16x8 A0[16], A1[16];
    {
        const size_t r_s0 = (size_t)(g * 256 + wv * 32 + l15) * DF;
        const size_t r_s1 = (size_t)(g * 256 + wv * 32 + 16 + l15) * DF;
#pragma unroll
        for (int t = 0; t < 16; ++t) {
            const float* s0 = x + r_s0 + t * 32 + quad * 8;
            const float* s1 = x + r_s1 + t * 32 + quad * 8;
            float4 a = *(const float4*)s0, b = *(const float4*)(s0 + 4);
            float4 c = *(const float4*)s1, d = *(const float4*)(s1 + 4);
            A0[t][0]=(short)bf16r(a.x); A0[t][1]=(short)bf16r(a.y);
            A0[t][2]=(short)bf16r(a.z); A0[t][3]=(short)bf16r(a.w);
            A0[t][4]=(short)bf16r(b.x); A0[t][5]=(short)bf16r(b.y);
            A0[t][6]=(short)bf16r(b.z); A0[t][7]=(short)bf16r(b.w);
            A1[t][0]=(short)bf16r(c.x); A1[t][1]=(short)bf16r(c.y);
            A1[t][2]=(short)bf16r(c.z); A1[t][3]=(short)bf16r(c.w);
            A1[t][4]=(short)bf16r(d.x); A1[t][5]=(short)bf16r(d.y);
            A1[t][6]=(short)bf16r(d.z); A1[t][7]=(short)bf16r(d.w);
        }
    }

    // ---- spin until all 64 blocks published their w1f slice --------------
    if (tid < 64) {
        long spins = 0;
        while (__hip_atomic_load(&doneflags[tid], __ATOMIC_ACQUIRE,
                                 __HIP_MEMORY_SCOPE_AGENT) != DONE_MAGIC
               && spins < 200000000L) { ++spins; __builtin_amdgcn_s_sleep(1); }
    }
    __syncthreads();
    __threadfence();

    // ---- Phase 1: GEMM, B double-buffered in LDS -------------------------
    {
        unsigned short* Bbase = (unsigned short*)smem;   // buf i at offset i*8192
        const uint4* wsrc = (const uint4*)w1f;
        uint4 pf0, pf1;
        pf0 = wsrc[tid * 2]; pf1 = wsrc[tid * 2 + 1];
        { uint4* d = (uint4*)Bbase; d[tid * 2] = pf0; d[tid * 2 + 1] = pf1; }
        __syncthreads();

        const float b2v = b2[0];
        float s_[2][4] = {{0,0,0,0},{0,0,0,0}};

        for (int cg = 0; cg < 64; ++cg) {
            const int buf = cg & 1;
            if (cg < 63) {
                const uint4* s = wsrc + (size_t)(cg + 1) * 1024;
                pf0 = s[tid * 2]; pf1 = s[tid * 2 + 1];
            }
            const unsigned short* bb = Bbase + buf * 8192 + l15 * 32 + quad * 8;
            f32x4 a00={0,0,0,0}, a01={0,0,0,0}, a10={0,0,0,0}, a11={0,0,0,0};
#pragma unroll
            for (int t = 0; t < 8; ++t) {
                bf16x8 Bf0 = *(const bf16x8*)(bb + t * 512);
                bf16x8 Bf1 = *(const bf16x8*)(bb + (t + 8) * 512);
                a00 = __builtin_amdgcn_mfma_f32_16x16x32_bf16(A0[t], Bf0, a00, 0, 0, 0);
                a10 = __builtin_amdgcn_mfma_f32_16x16x32_bf16(A1[t], Bf0, a10, 0, 0, 0);
                a01 = __builtin_amdgcn_mfma_f32_16x16x32_bf16(A0[t + 8], Bf1, a01, 0, 0, 0);
                a11 = __builtin_amdgcn_mfma_f32_16x16x32_bf16(A1[t + 8], Bf1, a11, 0, 0, 0);
            }
            const int col = cg * 16 + l15;
            const float b1c = b1[col], w2c = w2[col];
#pragma unroll
            for (int r = 0; r < 4; ++r) {
                float h0 = (a00[r] + a01[r]) + b1c; h0 = h0 > 0.f ? h0 : 0.f;
                s_[0][r] = fmaf(h0, w2c, s_[0][r]);
                float h1 = (a10[r] + a11[r]) + b1c; h1 = h1 > 0.f ? h1 : 0.f;
                s_[1][r] = fmaf(h1, w2c, s_[1][r]);
            }
            if (cg < 63) {
                uint4* d = (uint4*)(Bbase + (buf ^ 1) * 8192);
                d[tid * 2] = pf0; d[tid * 2 + 1] = pf1;
            }
            __syncthreads();
        }
        // reduce over 16 col-lanes; write f = sigmoid(z + b2) to LDS
#pragma unroll
        for (int sub = 0; sub < 2; ++sub)
#pragma unroll
            for (int r = 0; r < 4; ++r) {
                float v = s_[sub][r];
                v += __shfl_xor(v, 1, 16);
                v += __shfl_xor(v, 2, 16);
                v += __shfl_xor(v, 4, 16);
                v += __shfl_xor(v, 8, 16);
                if (l15 == 0) {
                    int rl = wv * 32 + sub * 16 + quad * 4 + r;
                    fS[rl] = 1.f / (1.f + expf(-(v + b2v)));
                }
            }
    }
    __syncthreads();

    // ---- Phase 2: persistence, both signs in parallel halves -------------
    const int h = tid >> 8;          // 0: sublevel, 1: superlevel
    const int ltid = tid & 255;
    char* sb = smem + h * 17408;
    unsigned* eks      = (unsigned*)sb;
    int*      comp     = (int*)(sb + 4096);
    unsigned* minE     = (unsigned*)(sb + 5120);
    int*      nxt      = (int*)(sb + 6144);
    int*      par2     = (int*)(sb + 7168);
    unsigned char* mfl = (unsigned char*)(sb + 8192);
    unsigned* mstK     = (unsigned*)(sb + 9216);
    unsigned* srt      = (unsigned*)(sb + 10240);
    int*      par      = (int*)(sb + 11264);
    int*      dr       = (int*)(sb + 12288);
    int*      cmaxr    = (int*)(sb + 13312);
    int*      order_   = (int*)(sb + 14336);
    int*      rank_    = (int*)(sb + 15360);
    float*    fvr      = (float*)(sb + 16384);

    {
        float f0 = fS[ltid];
        float fv = h ? -f0 : f0;
        unsigned em = encf(fv);
        int rk = 0;
#pragma unroll 8
        for (int j = 0; j < NODES; ++j) {
            float fj = fS[j];
            unsigned ej = encf(h ? -fj : fj);
            rk += (ej < em) || ((ej == em) && (j < ltid));
        }
        order_[rk] = ltid; rank_[ltid] = rk; fvr[rk] = fv;
        comp[ltid] = ltid; par[ltid] = ltid;
        dr[ltid] = -1; cmaxr[ltid] = 0; srt[ltid] = INF32;
    }
    __syncthreads();

    // edge keys for BOTH signs (2 edges / thread over 512 threads)
    {
        int* rank0 = (int*)(smem + 15360);
        int* rank1 = (int*)(smem + 17408 + 15360);
        unsigned* e0 = (unsigned*)smem;
        unsigned* e1 = (unsigned*)(smem + 17408);
        unsigned char* m0 = (unsigned char*)(smem + 8192);
        unsigned char* m1 = (unsigned char*)(smem + 17408 + 8192);
#pragma unroll
        for (int q = 0; q < 2; ++q) {
            int e = tid * 2 + q;
            int u = edges[2 * (g * EDGES + e)]     - g * NODES;
            int v = edges[2 * (g * EDGES + e) + 1] - g * NODES;
            if (u == v) { e0[e] = INF32; e1[e] = INF32; }
            else {
                int a0 = rank0[u], b0v = rank0[v];
                int lo0 = a0 < b0v ? a0 : b0v, hi0 = a0 < b0v ? b0v : a0;
                e0[e] = ((unsigned)hi0 << 18) | ((unsigned)e << 8) | (unsigned)lo0;
                int a1 = rank1[u], b1v = rank1[v];
                int lo1 = a1 < b1v ? a1 : b1v, hi1 = a1 < b1v ? b1v : a1;
                e1[e] = ((unsigned)hi1 << 18) | ((unsigned)e << 8) | (unsigned)lo1;
            }
            m0[e] = 0; m1[e] = 0;
        }
    }
    __syncthreads();

    // Boruvka (per half), joint early exit
    for (int round = 0; round < 8; ++round) {
        minE[ltid] = INF32;
        if (ltid == 0) chgA[h] = 0;
        __syncthreads();
#pragma unroll
        for (int q = 0; q < 4; ++q) {
            unsigned k = eks[ltid + q * 256];
            if (k != INF32) {
                int rlo = (int)(k & 255u), rhi = (int)(k >> 18);
                int cu = comp[rlo], cv = comp[rhi];
                if (cu != cv) { atomicMin(&minE[cu], k); atomicMin(&minE[cv], k); }
            }
        }
        __syncthreads();
        {
            unsigned mk = minE[ltid];
            int o = ltid;
            if (mk != INF32) {
                int rlo = (int)(mk & 255u), rhi = (int)(mk >> 18);
                int cu = comp[rlo], cv = comp[rhi];
                o = (cu == ltid) ? cv : cu;
                mfl[(mk >> 8) & 0x3FFu] = 1;
                chgA[h] = 1;
            }
            nxt[ltid] = o;
        }
        __syncthreads();
        if (chgA[0] + chgA[1] == 0) break;
        {
            int o = nxt[ltid];
            int p = o;
            if (nxt[o] == ltid && ltid < o) p = ltid;
            par2[ltid] = p;
        }
        __syncthreads();
        for (;;) {
            int p = par2[par2[ltid]];
            int conv = __syncthreads_and(p == par2[ltid]);
            if (conv) break;
            par2[ltid] = p;
            __syncthreads();
        }
        comp[ltid] = par2[comp[ltid]];
        __syncthreads();
    }

    // collect + counting-sort MST edges
    if (ltid == 0) cntA[h] = 0;
    __syncthreads();
#pragma unroll
    for (int q = 0; q < 4; ++q) {
        int e = ltid + q * 256;
        if (mfl[e]) { int p = atomicAdd(&cntA[h], 1); mstK[p] = eks[e]; }
    }
    __syncthreads();
    if (ltid >= cntA[h]) mstK[ltid] = INF32;
    __syncthreads();
    {
        unsigned myk = mstK[ltid];
        if (myk != INF32) {
            int pos = 0;
#pragma unroll 8
            for (int j = 0; j < NODES; ++j) pos += (mstK[j] < myk) ? 1 : 0;
            srt[pos] = myk;
        }
    }
    __syncthreads();

    // serial Kruskal replay (threads 0 and 256, concurrent waves)
    if (ltid == 0) {
        const int CNT = cntA[h];
        for (int s = 0; s < CNT; ++s) {
            unsigned k = srt[s];
            if (k == INF32) break;
            int rlo = (int)(k & 255u), rhi = (int)(k >> 18);
            int a = rlo; while (par[a] != a) { par[a] = par[par[a]]; a = par[a]; }
            int b = rhi; while (par[b] != b) { par[b] = par[par[b]]; b = par[b]; }
            if (a != b) {
                int elder = a < b ? a : b, young = a < b ? b : a;
                par[young] = elder;
                dr[young] = rhi;
            }
        }
    }
    __syncthreads();

    // component max (extended persistence), deaths -> LDS
    {
        int r = ltid;
        while (par[r] != r) r = par[r];
        atomicMax(&cmaxr[r], ltid);
        __syncthreads();
        float dv = (dr[ltid] >= 0) ? fvr[dr[ltid]] : fvr[cmaxr[r]];
        dl[h][order_[ltid]] = dv;
    }
    __syncthreads();

    // ---- Phase 3: phi MLPs + pooling + head ------------------------------
    {
        const float* wp = h ? wp1 : wp0;
        const float* bp = h ? bp1 : bp0;
        const float wa = wp[ltid], wb = wp[HP + ltid], bb = bp[ltid];
        float s = 0.f;
        for (int n = 0; n < NODES; ++n) {
            float f = fS[n], d = dl[h][n];
            float a = h ? fmaf(-d, wa, fmaf(f, wb, bb))
                        : fmaf(f, wa, fmaf(d, wb, bb));
            s += a > 0.f ? a : 0.f;
        }
        pp[h][ltid] = s;
    }
    __syncthreads();
    if (tid < NC) {
        float acc = bh[tid];
        for (int j = 0; j < HP; ++j)
            acc += pp[0][j] * wh[j * NC + tid] + pp[1][j] * wh[(HP + j) * NC + tid];
        out[g * NC + tid] = acc;   // f32 output
    }
}

extern "C" void kernel_launch(void* const* d_in, const int* in_sizes, int n_in,
                              void* d_out, int out_size, void* d_ws, size_t ws_size,
                              hipStream_t stream)
{
    const float* x   = (const float*)d_in[0];
    const int*   edg = (const int*)d_in[1];
    const float* w1  = (const float*)d_in[3];
    const float* b1  = (const float*)d_in[4];
    const float* w2  = (const float*)d_in[5];
    const float* b2  = (const float*)d_in[6];
    const float* wp0 = (const float*)d_in[7];
    const float* bp0 = (const float*)d_in[8];
    const float* wp1 = (const float*)d_in[9];
    const float* bp1 = (const float*)d_in[10];
    const float* wh  = (const float*)d_in[11];
    const float* bh  = (const float*)d_in[12];

    unsigned* doneflags = (unsigned*)d_ws;                         // 64 u32
    unsigned short* w1f = (unsigned short*)((char*)d_ws + 256);    // 1 MB

    k_all<<<NUM_GRAPHS, 512, 0, stream>>>(x, edg, w1, b1, w2, b2,
                                          wp0, bp0, wp1, bp1, wh, bh,
                                          doneflags, w1f, (float*)d_out);
}

// Round 18
// 240.009 us; speedup vs baseline: 1.2258x; 1.2258x over previous
//
#include <hip/hip_runtime.h>
#include <hip/hip_bf16.h>

#define NUM_GRAPHS 64
#define NODES 256
#define EDGES 1024
#define NTOT (NUM_GRAPHS * NODES) /* 16384 */
#define DF 512
#define HF 1024
#define HP 256
#define NC 10
#define INF32 0xFFFFFFFFu

typedef short bf16x8 __attribute__((ext_vector_type(8)));
typedef float f32x4 __attribute__((ext_vector_type(4)));

__device__ __forceinline__ unsigned short bf16r(float f) {
    __hip_bfloat16 h = __float2bfloat16(f);
    return *(unsigned short*)&h;
}
// monotone order-preserving encode for fp32 (bijection, works for +/-)
__device__ __forceinline__ unsigned encf(float x) {
    union { float f; unsigned u; } c; c.f = x;
    return (c.u & 0x80000000u) ? ~c.u : (c.u | 0x80000000u);
}

// ---- w1 (f32 [k][j]) -> w1f bf16, LANE-ORDERED MFMA B-fragment layout ----
// Element addr: ((cg*16 + t)*64 + lane)*8 shorts, lane = quad*16 + n16;
// lane holds B[k = t*32 + quad*8 + j][col = cg*16 + n16]. LDS reads at
// lane*16B: consecutive per lane -> conflict-free.
__global__ __launch_bounds__(256) void k_cvt_frag(
    const float* __restrict__ w1, unsigned short* __restrict__ w1f)
{
    __shared__ float ls[128 * 16];   // [kk][c], 8 KB
    const int tid = threadIdx.x;
    const int cg = blockIdx.x >> 2, kq = blockIdx.x & 3;
    const int c = tid & 15, kr = tid >> 4;
#pragma unroll
    for (int it = 0; it < 8; ++it) {
        int kk = it * 16 + kr;
        ls[kk * 16 + c] = w1[(size_t)(kq * 128 + kk) * HF + cg * 16 + c];
    }
    __syncthreads();
    const int tt = tid >> 6, n16 = tid & 15, q = (tid >> 4) & 3;
    unsigned short v[8];
#pragma unroll
    for (int j = 0; j < 8; ++j)
        v[j] = bf16r(ls[(tt * 32 + q * 8 + j) * 16 + n16]);
    // lane = q*16 + n16 ; t = kq*4 + tt
    size_t off = ((size_t)(cg * 16 + kq * 4 + tt) * 64 + (q * 16 + n16)) * 8;
#pragma unroll
    for (int j = 0; j < 8; ++j) w1f[off + j] = v[j];
}

// ------- Stage 1 (MFMA v5b): zbuf = relu(x@W1+b1)@w2 (pre-b2/sigmoid) -----
// 256 blocks x 64 rows. Wave wv owns 16 rows (A in 64 VGPR, direct from x);
// B double-buffered 2x16 KB LDS, lane-ordered (conflict-free reads), staged
// with FULL slab coverage (4 x uint4 per thread). One lane finishes each
// output row: plain store, no atomics.
__global__ __launch_bounds__(256, 2) void k_fil_mfma(
    const float* __restrict__ x, const unsigned short* __restrict__ w1f,
    const float* __restrict__ b1, const float* __restrict__ w2,
    float* __restrict__ zbuf)
{
    __shared__ unsigned short Bbuf[2 * 16 * 512];  // 2 x 16 KB
    const int tid = threadIdx.x;
    const int lane = tid & 63;
    const int wv = tid >> 6;            // wave 0..3 = row tile
    const int l15 = lane & 15, quad = lane >> 4;
    const int r0 = blockIdx.x * 64;
    const int row = r0 + wv * 16 + l15;

    // A fragments: row m=l15, k = t*32 + quad*8 + j ; f32 -> bf16 in regs
    bf16x8 A[16];
#pragma unroll
    for (int t = 0; t < 16; ++t) {
        const float* src = x + (size_t)row * DF + t * 32 + quad * 8;
        float4 v0 = *(const float4*)src;
        float4 v1 = *(const float4*)(src + 4);
        A[t][0] = (short)bf16r(v0.x); A[t][1] = (short)bf16r(v0.y);
        A[t][2] = (short)bf16r(v0.z); A[t][3] = (short)bf16r(v0.w);
        A[t][4] = (short)bf16r(v1.x); A[t][5] = (short)bf16r(v1.y);
        A[t][6] = (short)bf16r(v1.z); A[t][7] = (short)bf16r(v1.w);
    }

    // prime cg=0 into buf 0 (full 1024-uint4 slab: 4 chunks per thread)
    uint4 pf0, pf1, pf2, pf3;
    {
        const uint4* s = (const uint4*)w1f;
        pf0 = s[tid]; pf1 = s[tid + 256]; pf2 = s[tid + 512]; pf3 = s[tid + 768];
        uint4* d = (uint4*)Bbuf;
        d[tid] = pf0; d[tid + 256] = pf1; d[tid + 512] = pf2; d[tid + 768] = pf3;
    }
    __syncthreads();

    float s_[4] = {0.f, 0.f, 0.f, 0.f};

    for (int cg = 0; cg < 64; ++cg) {
        const int buf = cg & 1;
        if (cg < 63) {   // issue next-B loads; consumed after compute
            const uint4* s = (const uint4*)(w1f + (size_t)(cg + 1) * 8192);
            pf0 = s[tid]; pf1 = s[tid + 256];
            pf2 = s[tid + 512]; pf3 = s[tid + 768];
        }
        const unsigned short* bb = Bbuf + buf * 8192 + lane * 8;
        f32x4 acc0 = {0.f,0.f,0.f,0.f}, acc1 = {0.f,0.f,0.f,0.f};
#pragma unroll
        for (int t = 0; t < 8; ++t) {
            bf16x8 Bf0 = *(const bf16x8*)(bb + t * 512);
            bf16x8 Bf1 = *(const bf16x8*)(bb + (t + 8) * 512);
            acc0 = __builtin_amdgcn_mfma_f32_16x16x32_bf16(A[t], Bf0, acc0, 0, 0, 0);
            acc1 = __builtin_amdgcn_mfma_f32_16x16x32_bf16(A[t + 8], Bf1, acc1, 0, 0, 0);
        }
        const int col = cg * 16 + l15;
        const float b1c = b1[col], w2c = w2[col];
#pragma unroll
        for (int r = 0; r < 4; ++r) {
            float h = (acc0[r] + acc1[r]) + b1c;
            h = h > 0.f ? h : 0.f;
            s_[r] = fmaf(h, w2c, s_[r]);
        }
        if (cg < 63) {
            uint4* d = (uint4*)(Bbuf + (buf ^ 1) * 8192);
            d[tid] = pf0; d[tid + 256] = pf1;
            d[tid + 512] = pf2; d[tid + 768] = pf3;
        }
        __syncthreads();
    }

    // D row = quad*4 + r; reduce over the 16 col-lanes (l15); plain store
#pragma unroll
    for (int r = 0; r < 4; ++r) {
        float v = s_[r];
        v += __shfl_xor(v, 1, 16);
        v += __shfl_xor(v, 2, 16);
        v += __shfl_xor(v, 4, 16);
        v += __shfl_xor(v, 8, 16);
        if (l15 == 0) zbuf[r0 + wv * 16 + quad * 4 + r] = v;
    }
}

// ---------------- Stage 1 legacy (fp32 VALU) — ws_size fallback -----------
#define TN2 16
__global__ __launch_bounds__(256) void k_fil(
    const float* __restrict__ x, const float* __restrict__ w1,
    const float* __restrict__ b1, const float* __restrict__ w2,
    float* __restrict__ zout)
{
    __shared__ float xs[TN2][DF];
    __shared__ float part[256];
    const int tid = threadIdx.x;
    const int n0 = blockIdx.x * TN2;
    for (int c = tid; c < TN2 * DF / 4; c += 256) {
        int n = c >> 7, k4 = (c & 127) << 2;
        *(float4*)&xs[n][k4] = *(const float4*)(x + (size_t)(n0 + n) * DF + k4);
    }
    __syncthreads();
    float h[TN2][4];
#pragma unroll
    for (int n = 0; n < TN2; ++n)
#pragma unroll
        for (int q = 0; q < 4; ++q) h[n][q] = 0.f;
    for (int k = 0; k < DF; ++k) {
        float wr[4];
#pragma unroll
        for (int q = 0; q < 4; ++q) wr[q] = w1[(size_t)k * HF + tid + 256 * q];
#pragma unroll
        for (int n = 0; n < TN2; ++n) {
            float xv = xs[n][k];
#pragma unroll
            for (int q = 0; q < 4; ++q) h[n][q] = fmaf(xv, wr[q], h[n][q]);
        }
    }
    float b1r[4], w2r[4];
#pragma unroll
    for (int q = 0; q < 4; ++q) { b1r[q] = b1[tid + 256 * q]; w2r[q] = w2[tid + 256 * q]; }
    for (int n = 0; n < TN2; ++n) {
        float s = 0.f;
#pragma unroll
        for (int q = 0; q < 4; ++q) {
            float hv = h[n][q] + b1r[q];
            s += (hv > 0.f ? hv : 0.f) * w2r[q];
        }
        part[tid] = s;
        __syncthreads();
        for (int off = 128; off > 0; off >>= 1) {
            if (tid < off) part[tid] += part[tid + off];
            __syncthreads();
        }
        if (tid == 0) zout[n0 + n] = part[0];
        __syncthreads();
    }
}

// ------------- Stage 2: Boruvka MST filter + serial Kruskal replay --------
// (unchanged — verified structure)
__global__ __launch_bounds__(256) void k_pers(
    const int* __restrict__ edges, const float* __restrict__ zbuf,
    const float* __restrict__ b2, float* __restrict__ dout /* [2][NTOT] */)
{
    const int bid = blockIdx.x;
    const int g = bid >> 1, sgn = bid & 1;
    const int tid = threadIdx.x;

    __shared__ float fv[NODES];
    __shared__ unsigned long long vkey[NODES];
    __shared__ int order_[NODES], rank_[NODES];
    __shared__ float fvr[NODES];
    __shared__ unsigned eks[EDGES];
    __shared__ int comp[NODES];
    __shared__ unsigned minE[NODES];
    __shared__ int nxt[NODES], par2[NODES];
    __shared__ unsigned char mstflag[EDGES];
    __shared__ int cnt, chg;
    __shared__ unsigned mstK[NODES], srt[NODES];
    __shared__ int par[NODES], dr[NODES], cmaxr[NODES];

    float z0 = zbuf[g * NODES + tid];
    float f0 = 1.f / (1.f + expf(-(z0 + b2[0])));
    fv[tid] = sgn ? -f0 : f0;
    unsigned long long myk = ((unsigned long long)encf(fv[tid]) << 32) | (unsigned)tid;
    vkey[tid] = myk;
    srt[tid] = INF32; dr[tid] = -1; cmaxr[tid] = 0; par[tid] = tid;
    __syncthreads();

    // counting rank (keys unique): rank = #{j : key[j] < mine}
    int rk = 0;
#pragma unroll 8
    for (int j = 0; j < NODES; ++j) rk += (vkey[j] < myk) ? 1 : 0;
    order_[rk] = tid;
    rank_[tid] = rk;
    fvr[rk] = fv[tid];
    comp[tid] = tid;
    __syncthreads();

    // edge keys in rank domain; self-loops -> INF
#pragma unroll
    for (int q = 0; q < 4; ++q) {
        int e = tid + q * 256;
        int u = edges[2 * (g * EDGES + e)]     - g * NODES;
        int v = edges[2 * (g * EDGES + e) + 1] - g * NODES;
        if (u == v) { eks[e] = INF32; }
        else {
            int ra = rank_[u], rb = rank_[v];
            int rlo = ra < rb ? ra : rb, rhi = ra < rb ? rb : ra;
            eks[e] = ((unsigned)rhi << 18) | ((unsigned)e << 8) | (unsigned)rlo;
        }
        mstflag[e] = 0;
    }
    __syncthreads();

    // Boruvka with early exit + convergence-checked pointer jumping
    for (int round = 0; round < 8; ++round) {
        minE[tid] = INF32;
        if (tid == 0) chg = 0;
        __syncthreads();
#pragma unroll
        for (int q = 0; q < 4; ++q) {
            unsigned k = eks[tid + q * 256];
            if (k != INF32) {
                int rlo = (int)(k & 255u), rhi = (int)(k >> 18);
                int cu = comp[rlo], cv = comp[rhi];
                if (cu != cv) {
                    atomicMin(&minE[cu], k);
                    atomicMin(&minE[cv], k);
                }
            }
        }
        __syncthreads();
        {
            unsigned mk = minE[tid];
            int o = tid;
            if (mk != INF32) {
                int rlo = (int)(mk & 255u), rhi = (int)(mk >> 18);
                int cu = comp[rlo], cv = comp[rhi];
                o = (cu == tid) ? cv : cu;
                mstflag[(mk >> 8) & 0x3FFu] = 1;
                chg = 1;
            }
            nxt[tid] = o;
        }
        __syncthreads();
        if (!chg) break;
        {
            int o = nxt[tid];
            int p = o;
            if (nxt[o] == tid && tid < o) p = tid;
            par2[tid] = p;
        }
        __syncthreads();
        for (;;) {
            int p = par2[par2[tid]];
            int done = __syncthreads_and(p == par2[tid]);
            if (done) break;
            par2[tid] = p;
            __syncthreads();
        }
        comp[tid] = par2[comp[tid]];
        __syncthreads();
    }

    // collect MST edges (<=255)
    if (tid == 0) cnt = 0;
    __syncthreads();
#pragma unroll
    for (int q = 0; q < 4; ++q) {
        int e = tid + q * 256;
        if (mstflag[e]) {
            int p = atomicAdd(&cnt, 1);
            mstK[p] = eks[e];
        }
    }
    __syncthreads();
    if (tid >= cnt) mstK[tid] = INF32;
    __syncthreads();

    // counting sort of MST keys (unique among valid)
    unsigned myk2 = mstK[tid];
    if (myk2 != INF32) {
        int pos = 0;
#pragma unroll 8
        for (int j = 0; j < NODES; ++j) pos += (mstK[j] < myk2) ? 1 : 0;
        srt[pos] = myk2;
    }
    __syncthreads();

    // serial Kruskal replay (rank domain: elder = smaller rank, death=fvr[rhi])
    if (tid == 0) {
        for (int s = 0; s < NODES; ++s) {
            unsigned k = srt[s];
            if (k == INF32) break;
            int rlo = (int)(k & 255u), rhi = (int)(k >> 18);
            int a = rlo; while (par[a] != a) { par[a] = par[par[a]]; a = par[a]; }
            int b = rhi; while (par[b] != b) { par[b] = par[par[b]]; b = par[b]; }
            if (a != b) {
                int elder = a < b ? a : b, young = a < b ? b : a;
                par[young] = elder;
                dr[young] = rhi;
            }
        }
    }
    __syncthreads();

    // component max (extended persistence)
    int r = tid;
    while (par[r] != r) r = par[r];
    atomicMax(&cmaxr[r], tid);
    __syncthreads();

    float dv = (dr[tid] >= 0) ? fvr[dr[tid]] : fvr[cmaxr[r]];
    dout[sgn * NTOT + g * NODES + order_[tid]] = dv;
}

// ------- Stage 3: per-pair MLPs + segment sum + linear head (fused) -------
__global__ __launch_bounds__(256) void k_head(
    const float* __restrict__ zbuf, const float* __restrict__ b2,
    const float* __restrict__ dbuf,
    const float* __restrict__ wp0, const float* __restrict__ bp0,
    const float* __restrict__ wp1, const float* __restrict__ bp1,
    const float* __restrict__ wh, const float* __restrict__ bh,
    float* __restrict__ out)
{
    const int g = blockIdx.x, tid = threadIdx.x;
    __shared__ float lf[NODES], l0[NODES], l1[NODES];
    __shared__ float sp0[NODES], sp1[NODES];
    lf[tid] = 1.f / (1.f + expf(-(zbuf[g * NODES + tid] + b2[0])));
    l0[tid] = dbuf[g * NODES + tid];
    l1[tid] = dbuf[NTOT + g * NODES + tid];
    __syncthreads();
    const float w00 = wp0[tid], w01 = wp0[HP + tid], bb0 = bp0[tid];
    const float w10 = wp1[tid], w11 = wp1[HP + tid], bb1 = bp1[tid];
    float s0 = 0.f, s1 = 0.f;
    for (int n = 0; n < NODES; ++n) {
        float f = lf[n], d0 = l0[n], d1 = l1[n];
        float a0 = fmaf(f, w00, fmaf(d0, w01, bb0));      // h0 = (f, d_sub)
        float a1 = fmaf(-d1, w10, fmaf(f, w11, bb1));     // h1 = (-d_sup, f)
        s0 += a0 > 0.f ? a0 : 0.f;
        s1 += a1 > 0.f ? a1 : 0.f;
    }
    sp0[tid] = s0; sp1[tid] = s1;
    __syncthreads();
    if (tid < NC) {
        float acc = bh[tid];
        for (int j = 0; j < HP; ++j)
            acc += sp0[j] * wh[j * NC + tid] + sp1[j] * wh[(HP + j) * NC + tid];
        out[g * NC + tid] = acc;   // f32 output (reference dtype)
    }
}

extern "C" void kernel_launch(void* const* d_in, const int* in_sizes, int n_in,
                              void* d_out, int out_size, void* d_ws, size_t ws_size,
                              hipStream_t stream)
{
    const float* x   = (const float*)d_in[0];
    const int*   edg = (const int*)d_in[1];
    const float* w1  = (const float*)d_in[3];
    const float* b1  = (const float*)d_in[4];
    const float* w2  = (const float*)d_in[5];
    const float* b2  = (const float*)d_in[6];
    const float* wp0 = (const float*)d_in[7];
    const float* bp0 = (const float*)d_in[8];
    const float* wp1 = (const float*)d_in[9];
    const float* bp1 = (const float*)d_in[10];
    const float* wh  = (const float*)d_in[11];
    const float* bh  = (const float*)d_in[12];

    float* zbuf = (float*)d_ws;                       // [NTOT] f32 (pre-sigmoid)
    float* dbuf = zbuf + NTOT;                        // [2][NTOT] f32
    unsigned short* w1f = (unsigned short*)(dbuf + 2 * NTOT);  // 1 MB bf16

    const size_t WS_REQ = (size_t)3 * NTOT * 4 + (size_t)HF * DF * 2 + 256;

    if (ws_size >= WS_REQ) {
        k_cvt_frag<<<256, 256, 0, stream>>>(w1, w1f);
        k_fil_mfma<<<256, 256, 0, stream>>>(x, w1f, b1, w2, zbuf);
    } else {
        k_fil     <<<NTOT / TN2, 256, 0, stream>>>(x, w1, b1, w2, zbuf);
    }
    k_pers<<<NUM_GRAPHS * 2, 256, 0, stream>>>(edg, zbuf, b2, dbuf);
    k_head<<<NUM_GRAPHS, 256, 0, stream>>>(zbuf, b2, dbuf, wp0, bp0, wp1, bp1,
                                           wh, bh, (float*)d_out);
}

// Round 19
// 233.710 us; speedup vs baseline: 1.2589x; 1.0269x over previous
//
#include <hip/hip_runtime.h>
#include <hip/hip_bf16.h>

#define NUM_GRAPHS 64
#define NODES 256
#define EDGES 1024
#define NTOT (NUM_GRAPHS * NODES) /* 16384 */
#define DF 512
#define HF 1024
#define HP 256
#define NC 10
#define INF32 0xFFFFFFFFu

typedef short bf16x8 __attribute__((ext_vector_type(8)));
typedef float f32x4 __attribute__((ext_vector_type(4)));

__device__ __forceinline__ unsigned short bf16r(float f) {
    __hip_bfloat16 h = __float2bfloat16(f);
    return *(unsigned short*)&h;
}
// monotone order-preserving encode for fp32 (bijection, works for +/-)
__device__ __forceinline__ unsigned encf(float x) {
    union { float f; unsigned u; } c; c.f = x;
    return (c.u & 0x80000000u) ? ~c.u : (c.u | 0x80000000u);
}

// ---- w1 (f32 [k][j]) -> w1f bf16, LANE-ORDERED MFMA B-fragment layout ----
// Element addr: ((cg*16 + t)*64 + lane)*8 shorts, lane = quad*16 + n16;
// lane holds B[k = t*32 + quad*8 + j][col = cg*16 + n16].
__global__ __launch_bounds__(256) void k_cvt_frag(
    const float* __restrict__ w1, unsigned short* __restrict__ w1f)
{
    __shared__ float ls[128 * 16];   // [kk][c], 8 KB
    const int tid = threadIdx.x;
    const int cg = blockIdx.x >> 2, kq = blockIdx.x & 3;
    const int c = tid & 15, kr = tid >> 4;
#pragma unroll
    for (int it = 0; it < 8; ++it) {
        int kk = it * 16 + kr;
        ls[kk * 16 + c] = w1[(size_t)(kq * 128 + kk) * HF + cg * 16 + c];
    }
    __syncthreads();
    const int tt = tid >> 6, n16 = tid & 15, q = (tid >> 4) & 3;
    unsigned short v[8];
#pragma unroll
    for (int j = 0; j < 8; ++j)
        v[j] = bf16r(ls[(tt * 32 + q * 8 + j) * 16 + n16]);
    size_t off = ((size_t)(cg * 16 + kq * 4 + tt) * 64 + (q * 16 + n16)) * 8;
#pragma unroll
    for (int j = 0; j < 8; ++j) w1f[off + j] = v[j];
}

// ------- Stage 1 (MFMA v6): zbuf = relu(x@W1+b1)@w2 (pre-b2/sigmoid) ------
// 256 blocks x 64 rows x 256 thr. Wave wv: rows r0+(wv&1)*32..+32 (A in 128
// VGPR), cols half (wv>>1)*512..+512 (32 cgs). B quad-buffered 4x16 KB LDS;
// per-step staging of one cg per half. 4 independent MFMA chains. Partial
// sums joined across halves via LDS. Math identical to v5b (K split 2).
__global__ __launch_bounds__(256, 1) void k_fil_mfma(
    const float* __restrict__ x, const unsigned short* __restrict__ w1f,
    const float* __restrict__ b1, const float* __restrict__ w2,
    float* __restrict__ zbuf)
{
    __shared__ unsigned short Bbuf[4 * 16 * 512];  // 4 x 16 KB
    __shared__ float zpart[4][32];
    const int tid = threadIdx.x;
    const int lane = tid & 63;
    const int wv = tid >> 6;            // 0..3
    const int l15 = lane & 15, quad = lane >> 4;
    const int half = wv >> 1;           // column half (32 cgs)
    const int rt = wv & 1;              // row 32-tile
    const int r0 = blockIdx.x * 64;
    const int rowA = r0 + rt * 32 + l15;
    const int rowB = rowA + 16;

    // A fragments for 32 rows: two 16-row tiles, f32 -> bf16 in regs
    bf16x8 A0[16], A1[16];
#pragma unroll
    for (int t = 0; t < 16; ++t) {
        const float* s0 = x + (size_t)rowA * DF + t * 32 + quad * 8;
        const float* s1 = x + (size_t)rowB * DF + t * 32 + quad * 8;
        float4 a = *(const float4*)s0, b = *(const float4*)(s0 + 4);
        float4 c = *(const float4*)s1, d = *(const float4*)(s1 + 4);
        A0[t][0]=(short)bf16r(a.x); A0[t][1]=(short)bf16r(a.y);
        A0[t][2]=(short)bf16r(a.z); A0[t][3]=(short)bf16r(a.w);
        A0[t][4]=(short)bf16r(b.x); A0[t][5]=(short)bf16r(b.y);
        A0[t][6]=(short)bf16r(b.z); A0[t][7]=(short)bf16r(b.w);
        A1[t][0]=(short)bf16r(c.x); A1[t][1]=(short)bf16r(c.y);
        A1[t][2]=(short)bf16r(c.z); A1[t][3]=(short)bf16r(c.w);
        A1[t][4]=(short)bf16r(d.x); A1[t][5]=(short)bf16r(d.y);
        A1[t][6]=(short)bf16r(d.z); A1[t][7]=(short)bf16r(d.w);
    }

    // staging: threads 0-127 stage half 0, 128-255 stage half 1 (8 uint4 ea)
    const int t128 = tid & 127;
    const int sh = tid >> 7;
    uint4 pf[8];
    {
        const uint4* s = (const uint4*)(w1f + (size_t)(sh * 32) * 8192);
#pragma unroll
        for (int j = 0; j < 8; ++j) pf[j] = s[t128 + j * 128];
        uint4* d = (uint4*)Bbuf + (sh * 2 + 0) * 1024;
#pragma unroll
        for (int j = 0; j < 8; ++j) d[t128 + j * 128] = pf[j];
    }
    __syncthreads();

    float s_[2][4] = {{0,0,0,0},{0,0,0,0}};

    for (int i = 0; i < 32; ++i) {
        const int par = i & 1;
        if (i < 31) {
            const uint4* s = (const uint4*)(w1f + (size_t)(sh * 32 + i + 1) * 8192);
#pragma unroll
            for (int j = 0; j < 8; ++j) pf[j] = s[t128 + j * 128];
        }
        const unsigned short* bb = Bbuf + (half * 2 + par) * 8192 + lane * 8;
        f32x4 a00={0,0,0,0}, a01={0,0,0,0}, a10={0,0,0,0}, a11={0,0,0,0};
#pragma unroll
        for (int t = 0; t < 8; ++t) {
            bf16x8 Bf0 = *(const bf16x8*)(bb + t * 512);
            bf16x8 Bf1 = *(const bf16x8*)(bb + (t + 8) * 512);
            a00 = __builtin_amdgcn_mfma_f32_16x16x32_bf16(A0[t], Bf0, a00, 0, 0, 0);
            a10 = __builtin_amdgcn_mfma_f32_16x16x32_bf16(A1[t], Bf0, a10, 0, 0, 0);
            a01 = __builtin_amdgcn_mfma_f32_16x16x32_bf16(A0[t + 8], Bf1, a01, 0, 0, 0);
            a11 = __builtin_amdgcn_mfma_f32_16x16x32_bf16(A1[t + 8], Bf1, a11, 0, 0, 0);
        }
        const int col = (half * 32 + i) * 16 + l15;
        const float b1c = b1[col], w2c = w2[col];
#pragma unroll
        for (int r = 0; r < 4; ++r) {
            float h0 = (a00[r] + a01[r]) + b1c; h0 = h0 > 0.f ? h0 : 0.f;
            s_[0][r] = fmaf(h0, w2c, s_[0][r]);
            float h1 = (a10[r] + a11[r]) + b1c; h1 = h1 > 0.f ? h1 : 0.f;
            s_[1][r] = fmaf(h1, w2c, s_[1][r]);
        }
        if (i < 31) {
            uint4* d = (uint4*)Bbuf + (sh * 2 + (par ^ 1)) * 1024;
#pragma unroll
            for (int j = 0; j < 8; ++j) d[t128 + j * 128] = pf[j];
        }
        __syncthreads();
    }

    // reduce over 16 col-lanes; publish per-wave partials; join halves
#pragma unroll
    for (int sub = 0; sub < 2; ++sub)
#pragma unroll
        for (int r = 0; r < 4; ++r) {
            float v = s_[sub][r];
            v += __shfl_xor(v, 1, 16);
            v += __shfl_xor(v, 2, 16);
            v += __shfl_xor(v, 4, 16);
            v += __shfl_xor(v, 8, 16);
            if (l15 == 0) zpart[wv][sub * 16 + quad * 4 + r] = v;
        }
    __syncthreads();
    if (tid < 64) {
        int rrt = tid >> 5, idx = tid & 31;
        zbuf[r0 + tid] = zpart[rrt][idx] + zpart[rrt + 2][idx];
    }
}

// ---------------- Stage 1 legacy (fp32 VALU) — ws_size fallback -----------
#define TN2 16
__global__ __launch_bounds__(256) void k_fil(
    const float* __restrict__ x, const float* __restrict__ w1,
    const float* __restrict__ b1, const float* __restrict__ w2,
    float* __restrict__ zout)
{
    __shared__ float xs[TN2][DF];
    __shared__ float part[256];
    const int tid = threadIdx.x;
    const int n0 = blockIdx.x * TN2;
    for (int c = tid; c < TN2 * DF / 4; c += 256) {
        int n = c >> 7, k4 = (c & 127) << 2;
        *(float4*)&xs[n][k4] = *(const float4*)(x + (size_t)(n0 + n) * DF + k4);
    }
    __syncthreads();
    float h[TN2][4];
#pragma unroll
    for (int n = 0; n < TN2; ++n)
#pragma unroll
        for (int q = 0; q < 4; ++q) h[n][q] = 0.f;
    for (int k = 0; k < DF; ++k) {
        float wr[4];
#pragma unroll
        for (int q = 0; q < 4; ++q) wr[q] = w1[(size_t)k * HF + tid + 256 * q];
#pragma unroll
        for (int n = 0; n < TN2; ++n) {
            float xv = xs[n][k];
#pragma unroll
            for (int q = 0; q < 4; ++q) h[n][q] = fmaf(xv, wr[q], h[n][q]);
        }
    }
    float b1r[4], w2r[4];
#pragma unroll
    for (int q = 0; q < 4; ++q) { b1r[q] = b1[tid + 256 * q]; w2r[q] = w2[tid + 256 * q]; }
    for (int n = 0; n < TN2; ++n) {
        float s = 0.f;
#pragma unroll
        for (int q = 0; q < 4; ++q) {
            float hv = h[n][q] + b1r[q];
            s += (hv > 0.f ? hv : 0.f) * w2r[q];
        }
        part[tid] = s;
        __syncthreads();
        for (int off = 128; off > 0; off >>= 1) {
            if (tid < off) part[tid] += part[tid + off];
            __syncthreads();
        }
        if (tid == 0) zout[n0 + n] = part[0];
        __syncthreads();
    }
}

// ------------- Stage 2: Boruvka MST filter + serial Kruskal replay --------
// NEW: intra-component non-MST edges pruned to INF during the scan, killing
// late-round rescan + LDS-atomic contention.
__global__ __launch_bounds__(256) void k_pers(
    const int* __restrict__ edges, const float* __restrict__ zbuf,
    const float* __restrict__ b2, float* __restrict__ dout /* [2][NTOT] */)
{
    const int bid = blockIdx.x;
    const int g = bid >> 1, sgn = bid & 1;
    const int tid = threadIdx.x;

    __shared__ float fv[NODES];
    __shared__ unsigned long long vkey[NODES];
    __shared__ int order_[NODES], rank_[NODES];
    __shared__ float fvr[NODES];
    __shared__ unsigned eks[EDGES];
    __shared__ int comp[NODES];
    __shared__ unsigned minE[NODES];
    __shared__ int nxt[NODES], par2[NODES];
    __shared__ unsigned char mstflag[EDGES];
    __shared__ int cnt, chg;
    __shared__ unsigned mstK[NODES], srt[NODES];
    __shared__ int par[NODES], dr[NODES], cmaxr[NODES];

    float z0 = zbuf[g * NODES + tid];
    float f0 = 1.f / (1.f + expf(-(z0 + b2[0])));
    fv[tid] = sgn ? -f0 : f0;
    unsigned long long myk = ((unsigned long long)encf(fv[tid]) << 32) | (unsigned)tid;
    vkey[tid] = myk;
    srt[tid] = INF32; dr[tid] = -1; cmaxr[tid] = 0; par[tid] = tid;
    __syncthreads();

    // counting rank (keys unique): rank = #{j : key[j] < mine}
    int rk = 0;
#pragma unroll 8
    for (int j = 0; j < NODES; ++j) rk += (vkey[j] < myk) ? 1 : 0;
    order_[rk] = tid;
    rank_[tid] = rk;
    fvr[rk] = fv[tid];
    comp[tid] = tid;
    __syncthreads();

    // edge keys in rank domain; self-loops -> INF
#pragma unroll
    for (int q = 0; q < 4; ++q) {
        int e = tid + q * 256;
        int u = edges[2 * (g * EDGES + e)]     - g * NODES;
        int v = edges[2 * (g * EDGES + e) + 1] - g * NODES;
        if (u == v) { eks[e] = INF32; }
        else {
            int ra = rank_[u], rb = rank_[v];
            int rlo = ra < rb ? ra : rb, rhi = ra < rb ? rb : ra;
            eks[e] = ((unsigned)rhi << 18) | ((unsigned)e << 8) | (unsigned)rlo;
        }
        mstflag[e] = 0;
    }
    __syncthreads();

    // Boruvka with early exit, intra-comp pruning, convergence jumping
    for (int round = 0; round < 8; ++round) {
        minE[tid] = INF32;
        if (tid == 0) chg = 0;
        __syncthreads();
#pragma unroll
        for (int q = 0; q < 4; ++q) {
            int e = tid + q * 256;
            unsigned k = eks[e];
            if (k != INF32) {
                int rlo = (int)(k & 255u), rhi = (int)(k >> 18);
                int cu = comp[rlo], cv = comp[rhi];
                if (cu != cv) {
                    atomicMin(&minE[cu], k);
                    atomicMin(&minE[cv], k);
                } else if (!mstflag[e]) {
                    eks[e] = INF32;   // prune: never merges again
                }
            }
        }
        __syncthreads();
        {
            unsigned mk = minE[tid];
            int o = tid;
            if (mk != INF32) {
                int rlo = (int)(mk & 255u), rhi = (int)(mk >> 18);
                int cu = comp[rlo], cv = comp[rhi];
                o = (cu == tid) ? cv : cu;
                mstflag[(mk >> 8) & 0x3FFu] = 1;
                chg = 1;
            }
            nxt[tid] = o;
        }
        __syncthreads();
        if (!chg) break;
        {
            int o = nxt[tid];
            int p = o;
            if (nxt[o] == tid && tid < o) p = tid;
            par2[tid] = p;
        }
        __syncthreads();
        for (;;) {
            int p = par2[par2[tid]];
            int done = __syncthreads_and(p == par2[tid]);
            if (done) break;
            par2[tid] = p;
            __syncthreads();
        }
        comp[tid] = par2[comp[tid]];
        __syncthreads();
    }

    // collect MST edges (<=255)
    if (tid == 0) cnt = 0;
    __syncthreads();
#pragma unroll
    for (int q = 0; q < 4; ++q) {
        int e = tid + q * 256;
        if (mstflag[e]) {
            int p = atomicAdd(&cnt, 1);
            mstK[p] = eks[e];
        }
    }
    __syncthreads();
    if (tid >= cnt) mstK[tid] = INF32;
    __syncthreads();

    // counting sort of MST keys (unique among valid)
    unsigned myk2 = mstK[tid];
    if (myk2 != INF32) {
        int pos = 0;
#pragma unroll 8
        for (int j = 0; j < NODES; ++j) pos += (mstK[j] < myk2) ? 1 : 0;
        srt[pos] = myk2;
    }
    __syncthreads();

    // serial Kruskal replay (rank domain: elder = smaller rank, death=fvr[rhi])
    if (tid == 0) {
        for (int s = 0; s < NODES; ++s) {
            unsigned k = srt[s];
            if (k == INF32) break;
            int rlo = (int)(k & 255u), rhi = (int)(k >> 18);
            int a = rlo; while (par[a] != a) { par[a] = par[par[a]]; a = par[a]; }
            int b = rhi; while (par[b] != b) { par[b] = par[par[b]]; b = par[b]; }
            if (a != b) {
                int elder = a < b ? a : b, young = a < b ? b : a;
                par[young] = elder;
                dr[young] = rhi;
            }
        }
    }
    __syncthreads();

    // component max (extended persistence)
    int r = tid;
    while (par[r] != r) r = par[r];
    atomicMax(&cmaxr[r], tid);
    __syncthreads();

    float dv = (dr[tid] >= 0) ? fvr[dr[tid]] : fvr[cmaxr[r]];
    dout[sgn * NTOT + g * NODES + order_[tid]] = dv;
}

// ------- Stage 3: per-pair MLPs + segment sum + linear head (fused) -------
__global__ __launch_bounds__(256) void k_head(
    const float* __restrict__ zbuf, const float* __restrict__ b2,
    const float* __restrict__ dbuf,
    const float* __restrict__ wp0, const float* __restrict__ bp0,
    const float* __restrict__ wp1, const float* __restrict__ bp1,
    const float* __restrict__ wh, const float* __restrict__ bh,
    float* __restrict__ out)
{
    const int g = blockIdx.x, tid = threadIdx.x;
    __shared__ float lf[NODES], l0[NODES], l1[NODES];
    __shared__ float sp0[NODES], sp1[NODES];
    lf[tid] = 1.f / (1.f + expf(-(zbuf[g * NODES + tid] + b2[0])));
    l0[tid] = dbuf[g * NODES + tid];
    l1[tid] = dbuf[NTOT + g * NODES + tid];
    __syncthreads();
    const float w00 = wp0[tid], w01 = wp0[HP + tid], bb0 = bp0[tid];
    const float w10 = wp1[tid], w11 = wp1[HP + tid], bb1 = bp1[tid];
    float s0 = 0.f, s1 = 0.f;
    for (int n = 0; n < NODES; ++n) {
        float f = lf[n], d0 = l0[n], d1 = l1[n];
        float a0 = fmaf(f, w00, fmaf(d0, w01, bb0));      // h0 = (f, d_sub)
        float a1 = fmaf(-d1, w10, fmaf(f, w11, bb1));     // h1 = (-d_sup, f)
        s0 += a0 > 0.f ? a0 : 0.f;
        s1 += a1 > 0.f ? a1 : 0.f;
    }
    sp0[tid] = s0; sp1[tid] = s1;
    __syncthreads();
    if (tid < NC) {
        float acc = bh[tid];
        for (int j = 0; j < HP; ++j)
            acc += sp0[j] * wh[j * NC + tid] + sp1[j] * wh[(HP + j) * NC + tid];
        out[g * NC + tid] = acc;   // f32 output (reference dtype)
    }
}

extern "C" void kernel_launch(void* const* d_in, const int* in_sizes, int n_in,
                              void* d_out, int out_size, void* d_ws, size_t ws_size,
                              hipStream_t stream)
{
    const float* x   = (const float*)d_in[0];
    const int*   edg = (const int*)d_in[1];
    const float* w1  = (const float*)d_in[3];
    const float* b1  = (const float*)d_in[4];
    const float* w2  = (const float*)d_in[5];
    const float* b2  = (const float*)d_in[6];
    const float* wp0 = (const float*)d_in[7];
    const float* bp0 = (const float*)d_in[8];
    const float* wp1 = (const float*)d_in[9];
    const float* bp1 = (const float*)d_in[10];
    const float* wh  = (const float*)d_in[11];
    const float* bh  = (const float*)d_in[12];

    float* zbuf = (float*)d_ws;                       // [NTOT] f32 (pre-sigmoid)
    float* dbuf = zbuf + NTOT;                        // [2][NTOT] f32
    unsigned short* w1f = (unsigned short*)(dbuf + 2 * NTOT);  // 1 MB bf16

    const size_t WS_REQ = (size_t)3 * NTOT * 4 + (size_t)HF * DF * 2 + 256;

    if (ws_size >= WS_REQ) {
        k_cvt_frag<<<256, 256, 0, stream>>>(w1, w1f);
        k_fil_mfma<<<256, 256, 0, stream>>>(x, w1f, b1, w2, zbuf);
    } else {
        k_fil     <<<NTOT / TN2, 256, 0, stream>>>(x, w1, b1, w2, zbuf);
    }
    k_pers<<<NUM_GRAPHS * 2, 256, 0, stream>>>(edg, zbuf, b2, dbuf);
    k_head<<<NUM_GRAPHS, 256, 0, stream>>>(zbuf, b2, dbuf, wp0, bp0, wp1, bp1,
                                           wh, bh, (float*)d_out);
}